// Round 5
// baseline (221.105 us; speedup 1.0000x reference)
//
#include <hip/hip_runtime.h>
#include <hip/hip_bf16.h>

// Problem constants (RecurrentGCN / A3TGCN reduction)
constexpr int N_NODES = 20000;
constexpr int P_PER   = 12;
constexpr int N_EDGES = 640000;
constexpr int HID     = 100;

constexpr int BIN_W   = 64;                    // nodes per bin
constexpr int NB      = (N_NODES + BIN_W - 1) / BIN_W;   // 313 bins (last partial)
constexpr int BCAP    = 2560;                  // entries per bin; mean 2048, sigma 45 -> 11 sigma
constexpr int NBLK2   = 160;                   // partition blocks
constexpr int CHUNK   = N_EDGES / NBLK2;       // 4000
constexpr int CUR_STR = 16;                    // cursor padded to one per 64B line
constexpr int Y_STR   = 16;                    // y row stride (floats), 64B-aligned rows

// Workspace layout (4-byte elements)
constexpr size_t OFF_DINV  = 0;                               // N floats
constexpr size_t OFF_UZ    = OFF_DINV + N_NODES;              // 20000
constexpr size_t OFF_CZ    = OFF_UZ + HID;
constexpr size_t OFF_UH    = OFF_CZ + HID;
constexpr size_t OFF_CH    = OFF_UH + HID;
constexpr size_t OFF_PROBS = OFF_CH + HID;                    // 20400..20412
constexpr size_t OFF_CUR   = 20416;                           // NB*CUR_STR ints (5008)
constexpr size_t OFF_Y     = OFF_CUR + (size_t)NB * CUR_STR;  // 25424 (16-aligned), N*Y_STR floats
constexpr size_t OFF_SEG   = OFF_Y + (size_t)N_NODES * Y_STR; // 345424 (8B-aligned), NB*BCAP int2

// ---------------------------------------------------------------------------
// k1: tiny precompute — rank-1 collapse of (GCN weight @ Wl[:HID]) + softmax(att)
__global__ void precompute_kernel(const float* __restrict__ Wz, const float* __restrict__ bz,
                                  const float* __restrict__ Wh, const float* __restrict__ bh,
                                  const float* __restrict__ Wlz, const float* __restrict__ blz,
                                  const float* __restrict__ Wlh, const float* __restrict__ blh,
                                  const float* __restrict__ att,
                                  float* __restrict__ uz, float* __restrict__ cz,
                                  float* __restrict__ uh, float* __restrict__ ch,
                                  float* __restrict__ probs) {
    int t = threadIdx.x;
    if (t < HID) {
        float suz = 0.f, scz = 0.f, suh = 0.f, sch = 0.f;
        for (int j = 0; j < HID; ++j) {
            float wlz = Wlz[j * HID + t];   // only first HID rows of (2*HID,HID) matter (H0=0)
            float wlh = Wlh[j * HID + t];
            suz += Wz[j] * wlz;
            scz += bz[j] * wlz;
            suh += Wh[j] * wlh;
            sch += bh[j] * wlh;
        }
        uz[t] = suz;
        cz[t] = scz + blz[t];
        uh[t] = suh;
        ch[t] = sch + blh[t];
    }
    if (t == 0) {
        float m = att[0];
        for (int p = 1; p < P_PER; ++p) m = fmaxf(m, att[p]);
        float e[P_PER];
        float s = 0.f;
        for (int p = 0; p < P_PER; ++p) { e[p] = __expf(att[p] - m); s += e[p]; }
        float inv = 1.0f / s;
        for (int p = 0; p < P_PER; ++p) probs[p] = e[p] * inv;
    }
}

// k2: partition edges into NB bins of 64 dst-nodes.
// Pass 1: LDS histogram; one global cursor atomic per (block,bin) [50K total].
// Pass 2: contiguous per-(block,bin) runs -> ~13 edges = 102B contiguous writes.
// Entry: .x = src | (d_local<<16), .y = weight bits.
__global__ __launch_bounds__(256) void partition_kernel(const int* __restrict__ ei,
                                                        const float* __restrict__ w,
                                                        int* __restrict__ cur,
                                                        int2* __restrict__ seg) {
    __shared__ int hist[NB];
    __shared__ int base[NB];
    __shared__ int run[NB];
    int t = threadIdx.x;
    for (int b = t; b < NB; b += 256) { hist[b] = 0; run[b] = 0; }
    __syncthreads();
    int e0 = blockIdx.x * CHUNK;
    const int* __restrict__ dsts = ei + N_EDGES;
    for (int i = t; i < CHUNK; i += 256) {
        int d = dsts[e0 + i];
        atomicAdd(&hist[d >> 6], 1);
    }
    __syncthreads();
    for (int b = t; b < NB; b += 256) {
        int h = hist[b];
        base[b] = (h > 0) ? atomicAdd(cur + (size_t)b * CUR_STR, h) : 0;
    }
    __syncthreads();
    for (int i = t; i < CHUNK; i += 256) {
        int s = ei[e0 + i];
        int d = dsts[e0 + i];
        float wt = w[e0 + i];
        int b = d >> 6;
        int pos = base[b] + atomicAdd(&run[b], 1);
        if (pos < BCAP)
            seg[(size_t)b * BCAP + pos] = make_int2(s | ((d & 63) << 16), __float_as_int(wt));
    }
}

// k3: per bin — wsum[n] via LDS float atomics; dinv[n] = rsqrt(1+wsum); y[n,:] = dinv*x[n,:]
__global__ __launch_bounds__(256) void degdinv_y_kernel(const int2* __restrict__ seg,
                                                        const int* __restrict__ cur,
                                                        const float* __restrict__ x,
                                                        float* __restrict__ dinv,
                                                        float* __restrict__ y) {
    __shared__ float wsum[BIN_W];
    int t = threadIdx.x;
    int b = blockIdx.x;
    if (t < BIN_W) wsum[t] = 0.f;
    __syncthreads();
    int c = min(cur[(size_t)b * CUR_STR], BCAP);
    const int2* sg = seg + (size_t)b * BCAP;
    for (int i = t; i < c; i += 256) {
        int2 e = sg[i];
        atomicAdd(&wsum[e.x >> 16], __int_as_float(e.y));
    }
    __syncthreads();
    if (t < BIN_W) wsum[t] = rsqrtf(1.0f + wsum[t]);
    __syncthreads();
    int n0 = b * BIN_W;
    if (t < BIN_W && n0 + t < N_NODES) dinv[n0 + t] = wsum[t];
    for (int i = t; i < BIN_W * P_PER; i += 256) {
        int nl = i / P_PER, p = i - nl * P_PER;
        int n = n0 + nl;
        if (n < N_NODES) y[(size_t)n * Y_STR + p] = wsum[nl] * x[(size_t)n * P_PER + p];
    }
}

// k4: per bin — stream edges, accumulate w*y[s,:] into padded LDS agg via ds_add_f32;
// then finalize 64 nodes x 4 lanes: a = dn*(agg + y[n]);
// out[n] = bout + sum_k relu( sum_p probs[p]*sigmoid(-(a*uz+cz))*tanh(a*uh+ch) )*Wout[k]
__global__ __launch_bounds__(256) void gather_finalize_kernel(const int2* __restrict__ seg,
                                                              const int* __restrict__ cur,
                                                              const float* __restrict__ y,
                                                              const float* __restrict__ dinv,
                                                              const float* __restrict__ uz,
                                                              const float* __restrict__ cz,
                                                              const float* __restrict__ uh,
                                                              const float* __restrict__ ch,
                                                              const float* __restrict__ probs,
                                                              const float* __restrict__ Wout,
                                                              const float* __restrict__ bout,
                                                              float* __restrict__ out) {
    __shared__ float s_uz[HID], s_cz[HID], s_uh[HID], s_ch[HID], s_wo[HID];
    __shared__ float s_pr[P_PER];
    __shared__ float agg[BIN_W][P_PER + 1];    // pad 13: odd stride breaks bank aliasing
    int t = threadIdx.x;
    if (t < HID) {
        s_uz[t] = uz[t]; s_cz[t] = cz[t];
        s_uh[t] = uh[t]; s_ch[t] = ch[t];
        s_wo[t] = Wout[t];
    }
    if (t < P_PER) s_pr[t] = probs[t];
    for (int i = t; i < BIN_W * (P_PER + 1); i += 256) ((float*)agg)[i] = 0.f;
    __syncthreads();

    int b = blockIdx.x;
    int c = min(cur[(size_t)b * CUR_STR], BCAP);
    const int2* sg = seg + (size_t)b * BCAP;
    for (int i = t; i < c; i += 256) {
        int2 e = sg[i];
        int s  = e.x & 0xFFFF;
        int dl = e.x >> 16;
        float wt = __int_as_float(e.y);
        const float4* yr = (const float4*)(y + (size_t)s * Y_STR);
        float4 y0 = yr[0], y1 = yr[1], y2 = yr[2];
        atomicAdd(&agg[dl][0],  wt * y0.x);  atomicAdd(&agg[dl][1],  wt * y0.y);
        atomicAdd(&agg[dl][2],  wt * y0.z);  atomicAdd(&agg[dl][3],  wt * y0.w);
        atomicAdd(&agg[dl][4],  wt * y1.x);  atomicAdd(&agg[dl][5],  wt * y1.y);
        atomicAdd(&agg[dl][6],  wt * y1.z);  atomicAdd(&agg[dl][7],  wt * y1.w);
        atomicAdd(&agg[dl][8],  wt * y2.x);  atomicAdd(&agg[dl][9],  wt * y2.y);
        atomicAdd(&agg[dl][10], wt * y2.z);  atomicAdd(&agg[dl][11], wt * y2.w);
    }
    __syncthreads();

    // finalize: 4 lanes per node, 64 nodes per block
    int nl = t >> 2;
    int l  = t & 3;
    int n  = b * BIN_W + nl;
    if (n >= N_NODES) return;
    float dn = dinv[n];
    float a[P_PER];
    {
        const float4* yr = (const float4*)(y + (size_t)n * Y_STR);
        float4 y0 = yr[0], y1 = yr[1], y2 = yr[2];
        a[0]  = dn * (agg[nl][0]  + y0.x);  a[1]  = dn * (agg[nl][1]  + y0.y);
        a[2]  = dn * (agg[nl][2]  + y0.z);  a[3]  = dn * (agg[nl][3]  + y0.w);
        a[4]  = dn * (agg[nl][4]  + y1.x);  a[5]  = dn * (agg[nl][5]  + y1.y);
        a[6]  = dn * (agg[nl][6]  + y1.z);  a[7]  = dn * (agg[nl][7]  + y1.w);
        a[8]  = dn * (agg[nl][8]  + y2.x);  a[9]  = dn * (agg[nl][9]  + y2.y);
        a[10] = dn * (agg[nl][10] + y2.z);  a[11] = dn * (agg[nl][11] + y2.w);
    }
    float rk = 0.f;
    for (int k = l; k < HID; k += 4) {      // 25 iterations per lane, uniform
        float uzk = s_uz[k], czk = s_cz[k], uhk = s_uh[k], chk = s_ch[k];
        float a2 = 0.f;
#pragma unroll
        for (int p = 0; p < P_PER; ++p) {
            float av = a[p];
            float vz = fminf(fmaxf(av * uzk + czk, -30.f), 30.f);
            float vh = fminf(fmaxf(av * uhk + chk, -15.f), 15.f);
            float ez  = __expf(vz);
            float e2h = __expf(2.0f * vh);
            float term = (e2h - 1.0f) / ((1.0f + ez) * (e2h + 1.0f));  // sigmoid(-vz)*tanh(vh)
            a2 += s_pr[p] * term;
        }
        rk += fmaxf(a2, 0.0f) * s_wo[k];
    }
    rk += __shfl_xor(rk, 1, 64);
    rk += __shfl_xor(rk, 2, 64);
    if (l == 0) out[n] = rk + bout[0];
}

extern "C" void kernel_launch(void* const* d_in, const int* in_sizes, int n_in,
                              void* d_out, int out_size, void* d_ws, size_t ws_size,
                              hipStream_t stream) {
    const float* x   = (const float*)d_in[0];
    const int*   ei  = (const int*)d_in[1];
    const float* ew  = (const float*)d_in[2];
    const float* Wz  = (const float*)d_in[3];
    const float* bz  = (const float*)d_in[4];
    // d_in[5], d_in[6]: W_r, b_r — dead (H0 = 0)
    const float* Wh  = (const float*)d_in[7];
    const float* bh  = (const float*)d_in[8];
    const float* Wlz = (const float*)d_in[9];
    const float* blz = (const float*)d_in[10];
    // d_in[11], d_in[12]: Wl_r, bl_r — dead
    const float* Wlh = (const float*)d_in[13];
    const float* blh = (const float*)d_in[14];
    const float* att = (const float*)d_in[15];
    const float* Wout = (const float*)d_in[16];
    const float* bout = (const float*)d_in[17];
    float* out = (float*)d_out;

    float* ws    = (float*)d_ws;
    float* dinv  = ws + OFF_DINV;
    float* uz    = ws + OFF_UZ;
    float* cz    = ws + OFF_CZ;
    float* uh    = ws + OFF_UH;
    float* ch    = ws + OFF_CH;
    float* probs = ws + OFF_PROBS;
    int*   cur   = (int*)(ws + OFF_CUR);
    float* y     = ws + OFF_Y;
    int2*  seg   = (int2*)(ws + OFF_SEG);

    hipMemsetAsync(cur, 0, (size_t)NB * CUR_STR * sizeof(int), stream);
    hipLaunchKernelGGL(precompute_kernel, dim3(1), dim3(128), 0, stream,
                       Wz, bz, Wh, bh, Wlz, blz, Wlh, blh, att, uz, cz, uh, ch, probs);
    hipLaunchKernelGGL(partition_kernel, dim3(NBLK2), dim3(256), 0, stream,
                       ei, ew, cur, seg);
    hipLaunchKernelGGL(degdinv_y_kernel, dim3(NB), dim3(256), 0, stream,
                       seg, cur, x, dinv, y);
    hipLaunchKernelGGL(gather_finalize_kernel, dim3(NB), dim3(256), 0, stream,
                       seg, cur, y, dinv, uz, cz, uh, ch, probs, Wout, bout, out);
}

// Round 6
// 214.425 us; speedup vs baseline: 1.0312x; 1.0312x over previous
//
#include <hip/hip_runtime.h>
#include <hip/hip_bf16.h>

// Problem constants (RecurrentGCN / A3TGCN reduction)
constexpr int N_NODES = 20000;
constexpr int P_PER   = 12;
constexpr int N_EDGES = 640000;
constexpr int HID     = 100;

constexpr int BIN_W   = 64;                    // nodes per bin
constexpr int NB      = (N_NODES + BIN_W - 1) / BIN_W;   // 313 bins (last partial)
constexpr int BCAP    = 2560;                  // entries per bin; mean 2048, sigma 45 -> 11 sigma
constexpr int NBLK2   = 160;                   // partition blocks
constexpr int CHUNK   = N_EDGES / NBLK2;       // 4000
constexpr int CUR_STR = 16;                    // cursor padded to one per 64B line
constexpr int Y_STR   = 16;                    // y row stride (floats), 64B-aligned rows
constexpr int SUB     = 8;                     // gather sub-blocks per bin (TLP for latency hiding)

// Workspace layout (4-byte elements)
constexpr size_t OFF_DINV  = 0;                               // N floats
constexpr size_t OFF_UZ    = OFF_DINV + N_NODES;              // 20000
constexpr size_t OFF_CZ    = OFF_UZ + HID;
constexpr size_t OFF_UH    = OFF_CZ + HID;
constexpr size_t OFF_CH    = OFF_UH + HID;
constexpr size_t OFF_PROBS = OFF_CH + HID;                    // 20400..20412
constexpr size_t OFF_CUR   = 20416;                           // NB*CUR_STR ints (5008)
constexpr size_t OFF_Y     = OFF_CUR + (size_t)NB * CUR_STR;  // 25424 (16-aligned), N*Y_STR floats
constexpr size_t OFF_SEG   = OFF_Y + (size_t)N_NODES * Y_STR; // 345424, NB*BCAP int2
constexpr size_t OFF_PART  = OFF_SEG + (size_t)NB * BCAP * 2; // 1947984 (16B-aligned), NB*SUB*BIN_W*P_PER floats (~7.7MB)

// ---------------------------------------------------------------------------
// k1: tiny precompute — rank-1 collapse of (GCN weight @ Wl[:HID]) + softmax(att)
__global__ void precompute_kernel(const float* __restrict__ Wz, const float* __restrict__ bz,
                                  const float* __restrict__ Wh, const float* __restrict__ bh,
                                  const float* __restrict__ Wlz, const float* __restrict__ blz,
                                  const float* __restrict__ Wlh, const float* __restrict__ blh,
                                  const float* __restrict__ att,
                                  float* __restrict__ uz, float* __restrict__ cz,
                                  float* __restrict__ uh, float* __restrict__ ch,
                                  float* __restrict__ probs) {
    int t = threadIdx.x;
    if (t < HID) {
        float suz = 0.f, scz = 0.f, suh = 0.f, sch = 0.f;
        for (int j = 0; j < HID; ++j) {
            float wlz = Wlz[j * HID + t];   // only first HID rows of (2*HID,HID) matter (H0=0)
            float wlh = Wlh[j * HID + t];
            suz += Wz[j] * wlz;
            scz += bz[j] * wlz;
            suh += Wh[j] * wlh;
            sch += bh[j] * wlh;
        }
        uz[t] = suz;
        cz[t] = scz + blz[t];
        uh[t] = suh;
        ch[t] = sch + blh[t];
    }
    if (t == 0) {
        float m = att[0];
        for (int p = 1; p < P_PER; ++p) m = fmaxf(m, att[p]);
        float e[P_PER];
        float s = 0.f;
        for (int p = 0; p < P_PER; ++p) { e[p] = __expf(att[p] - m); s += e[p]; }
        float inv = 1.0f / s;
        for (int p = 0; p < P_PER; ++p) probs[p] = e[p] * inv;
    }
}

// k2: partition edges into NB bins of 64 dst-nodes.
// Pass 1: LDS histogram; one global cursor atomic per (block,bin) [50K total].
// Pass 2: contiguous per-(block,bin) runs. Entry: .x = src | (d_local<<16), .y = w bits.
__global__ __launch_bounds__(256) void partition_kernel(const int* __restrict__ ei,
                                                        const float* __restrict__ w,
                                                        int* __restrict__ cur,
                                                        int2* __restrict__ seg) {
    __shared__ int hist[NB];
    __shared__ int base[NB];
    __shared__ int run[NB];
    int t = threadIdx.x;
    for (int b = t; b < NB; b += 256) { hist[b] = 0; run[b] = 0; }
    __syncthreads();
    int e0 = blockIdx.x * CHUNK;
    const int* __restrict__ dsts = ei + N_EDGES;
    for (int i = t; i < CHUNK; i += 256) {
        int d = dsts[e0 + i];
        atomicAdd(&hist[d >> 6], 1);
    }
    __syncthreads();
    for (int b = t; b < NB; b += 256) {
        int h = hist[b];
        base[b] = (h > 0) ? atomicAdd(cur + (size_t)b * CUR_STR, h) : 0;
    }
    __syncthreads();
    for (int i = t; i < CHUNK; i += 256) {
        int s = ei[e0 + i];
        int d = dsts[e0 + i];
        float wt = w[e0 + i];
        int b = d >> 6;
        int pos = base[b] + atomicAdd(&run[b], 1);
        if (pos < BCAP)
            seg[(size_t)b * BCAP + pos] = make_int2(s | ((d & 63) << 16), __float_as_int(wt));
    }
}

// k3: per bin — wsum[n] via LDS float atomics; dinv[n] = rsqrt(1+wsum); y[n,:] = dinv*x[n,:]
__global__ __launch_bounds__(256) void degdinv_y_kernel(const int2* __restrict__ seg,
                                                        const int* __restrict__ cur,
                                                        const float* __restrict__ x,
                                                        float* __restrict__ dinv,
                                                        float* __restrict__ y) {
    __shared__ float wsum[BIN_W];
    int t = threadIdx.x;
    int b = blockIdx.x;
    if (t < BIN_W) wsum[t] = 0.f;
    __syncthreads();
    int c = min(cur[(size_t)b * CUR_STR], BCAP);
    const int2* sg = seg + (size_t)b * BCAP;
    for (int i = t; i < c; i += 256) {
        int2 e = sg[i];
        atomicAdd(&wsum[e.x >> 16], __int_as_float(e.y));
    }
    __syncthreads();
    if (t < BIN_W) wsum[t] = rsqrtf(1.0f + wsum[t]);
    __syncthreads();
    int n0 = b * BIN_W;
    if (t < BIN_W && n0 + t < N_NODES) dinv[n0 + t] = wsum[t];
    for (int i = t; i < BIN_W * P_PER; i += 256) {
        int nl = i / P_PER, p = i - nl * P_PER;
        int n = n0 + nl;
        if (n < N_NODES) y[(size_t)n * Y_STR + p] = wsum[nl] * x[(size_t)n * P_PER + p];
    }
}

// k4: partial gather — SUB sub-blocks per bin for wave-level latency hiding.
// Each sub-block: ~256 edges, LDS agg[64][13] via ds_add, then one contiguous
// 64x12-float partial write. No global atomics.
__global__ __launch_bounds__(256) void gather_partial_kernel(const int2* __restrict__ seg,
                                                             const int* __restrict__ cur,
                                                             const float* __restrict__ y,
                                                             float* __restrict__ part) {
    __shared__ float agg[BIN_W][P_PER + 1];    // pad 13: odd stride breaks bank aliasing
    int t = threadIdx.x;
    int b   = blockIdx.x >> 3;     // bin
    int sub = blockIdx.x & (SUB - 1);
    for (int i = t; i < BIN_W * (P_PER + 1); i += 256) ((float*)agg)[i] = 0.f;
    __syncthreads();
    int c = min(cur[(size_t)b * CUR_STR], BCAP);
    const int2* sg = seg + (size_t)b * BCAP;
    for (int i = sub * 256 + t; i < c; i += SUB * 256) {
        int2 e = sg[i];
        int s  = e.x & 0xFFFF;
        int dl = e.x >> 16;
        float wt = __int_as_float(e.y);
        const float4* yr = (const float4*)(y + (size_t)s * Y_STR);
        float4 y0 = yr[0], y1 = yr[1], y2 = yr[2];
        atomicAdd(&agg[dl][0],  wt * y0.x);  atomicAdd(&agg[dl][1],  wt * y0.y);
        atomicAdd(&agg[dl][2],  wt * y0.z);  atomicAdd(&agg[dl][3],  wt * y0.w);
        atomicAdd(&agg[dl][4],  wt * y1.x);  atomicAdd(&agg[dl][5],  wt * y1.y);
        atomicAdd(&agg[dl][6],  wt * y1.z);  atomicAdd(&agg[dl][7],  wt * y1.w);
        atomicAdd(&agg[dl][8],  wt * y2.x);  atomicAdd(&agg[dl][9],  wt * y2.y);
        atomicAdd(&agg[dl][10], wt * y2.z);  atomicAdd(&agg[dl][11], wt * y2.w);
    }
    __syncthreads();
    if (t < BIN_W) {
        float4* d4 = (float4*)(part + ((size_t)blockIdx.x * BIN_W + t) * P_PER);
        d4[0] = make_float4(agg[t][0], agg[t][1], agg[t][2],  agg[t][3]);
        d4[1] = make_float4(agg[t][4], agg[t][5], agg[t][6],  agg[t][7]);
        d4[2] = make_float4(agg[t][8], agg[t][9], agg[t][10], agg[t][11]);
    }
}

// k5: finalize — sum SUB partials per node, a = dn*(sum + y[n]), then
// out[n] = bout + sum_k relu( sum_p probs[p]*sigmoid(-(a*uz+cz))*tanh(a*uh+ch) )*Wout[k]
// 4 lanes per node, 64 nodes per block (313 blocks).
__global__ __launch_bounds__(256) void finalize_kernel(const float* __restrict__ part,
                                                       const float* __restrict__ y,
                                                       const float* __restrict__ dinv,
                                                       const float* __restrict__ uz,
                                                       const float* __restrict__ cz,
                                                       const float* __restrict__ uh,
                                                       const float* __restrict__ ch,
                                                       const float* __restrict__ probs,
                                                       const float* __restrict__ Wout,
                                                       const float* __restrict__ bout,
                                                       float* __restrict__ out) {
    __shared__ float s_uz[HID], s_cz[HID], s_uh[HID], s_ch[HID], s_wo[HID];
    __shared__ float s_pr[P_PER];
    int t = threadIdx.x;
    if (t < HID) {
        s_uz[t] = uz[t]; s_cz[t] = cz[t];
        s_uh[t] = uh[t]; s_ch[t] = ch[t];
        s_wo[t] = Wout[t];
    }
    if (t < P_PER) s_pr[t] = probs[t];
    __syncthreads();

    int b  = blockIdx.x;
    int nl = t >> 2;
    int l  = t & 3;
    int n  = b * BIN_W + nl;
    if (n >= N_NODES) return;

    float a[P_PER];
#pragma unroll
    for (int p = 0; p < P_PER; ++p) a[p] = 0.f;
    // lane l sums partials sub = l and l+4
    for (int s2 = l; s2 < SUB; s2 += 4) {
        const float4* pr = (const float4*)(part + ((size_t)(b * SUB + s2) * BIN_W + nl) * P_PER);
        float4 p0 = pr[0], p1 = pr[1], p2 = pr[2];
        a[0]  += p0.x;  a[1]  += p0.y;  a[2]  += p0.z;  a[3]  += p0.w;
        a[4]  += p1.x;  a[5]  += p1.y;  a[6]  += p1.z;  a[7]  += p1.w;
        a[8]  += p2.x;  a[9]  += p2.y;  a[10] += p2.z;  a[11] += p2.w;
    }
    // reduce across the 4-lane group (lanes 4*q..4*q+3 of the wave)
#pragma unroll
    for (int off = 1; off <= 2; off <<= 1) {
#pragma unroll
        for (int p = 0; p < P_PER; ++p) a[p] += __shfl_xor(a[p], off, 64);
    }
    {
        float dn = dinv[n];
        const float4* yr = (const float4*)(y + (size_t)n * Y_STR);
        float4 y0 = yr[0], y1 = yr[1], y2 = yr[2];
        a[0]  = dn * (a[0]  + y0.x);  a[1]  = dn * (a[1]  + y0.y);
        a[2]  = dn * (a[2]  + y0.z);  a[3]  = dn * (a[3]  + y0.w);
        a[4]  = dn * (a[4]  + y1.x);  a[5]  = dn * (a[5]  + y1.y);
        a[6]  = dn * (a[6]  + y1.z);  a[7]  = dn * (a[7]  + y1.w);
        a[8]  = dn * (a[8]  + y2.x);  a[9]  = dn * (a[9]  + y2.y);
        a[10] = dn * (a[10] + y2.z);  a[11] = dn * (a[11] + y2.w);
    }
    float rk = 0.f;
    for (int k = l; k < HID; k += 4) {      // 25 iterations per lane, uniform
        float uzk = s_uz[k], czk = s_cz[k], uhk = s_uh[k], chk = s_ch[k];
        float a2 = 0.f;
#pragma unroll
        for (int p = 0; p < P_PER; ++p) {
            float av = a[p];
            float vz = fminf(fmaxf(av * uzk + czk, -30.f), 30.f);
            float vh = fminf(fmaxf(av * uhk + chk, -15.f), 15.f);
            float ez  = __expf(vz);
            float e2h = __expf(2.0f * vh);
            float term = (e2h - 1.0f) / ((1.0f + ez) * (e2h + 1.0f));  // sigmoid(-vz)*tanh(vh)
            a2 += s_pr[p] * term;
        }
        rk += fmaxf(a2, 0.0f) * s_wo[k];
    }
    rk += __shfl_xor(rk, 1, 64);
    rk += __shfl_xor(rk, 2, 64);
    if (l == 0) out[n] = rk + bout[0];
}

extern "C" void kernel_launch(void* const* d_in, const int* in_sizes, int n_in,
                              void* d_out, int out_size, void* d_ws, size_t ws_size,
                              hipStream_t stream) {
    const float* x   = (const float*)d_in[0];
    const int*   ei  = (const int*)d_in[1];
    const float* ew  = (const float*)d_in[2];
    const float* Wz  = (const float*)d_in[3];
    const float* bz  = (const float*)d_in[4];
    // d_in[5], d_in[6]: W_r, b_r — dead (H0 = 0)
    const float* Wh  = (const float*)d_in[7];
    const float* bh  = (const float*)d_in[8];
    const float* Wlz = (const float*)d_in[9];
    const float* blz = (const float*)d_in[10];
    // d_in[11], d_in[12]: Wl_r, bl_r — dead
    const float* Wlh = (const float*)d_in[13];
    const float* blh = (const float*)d_in[14];
    const float* att = (const float*)d_in[15];
    const float* Wout = (const float*)d_in[16];
    const float* bout = (const float*)d_in[17];
    float* out = (float*)d_out;

    float* ws    = (float*)d_ws;
    float* dinv  = ws + OFF_DINV;
    float* uz    = ws + OFF_UZ;
    float* cz    = ws + OFF_CZ;
    float* uh    = ws + OFF_UH;
    float* ch    = ws + OFF_CH;
    float* probs = ws + OFF_PROBS;
    int*   cur   = (int*)(ws + OFF_CUR);
    float* y     = ws + OFF_Y;
    int2*  seg   = (int2*)(ws + OFF_SEG);
    float* part  = ws + OFF_PART;

    hipMemsetAsync(cur, 0, (size_t)NB * CUR_STR * sizeof(int), stream);
    hipLaunchKernelGGL(precompute_kernel, dim3(1), dim3(128), 0, stream,
                       Wz, bz, Wh, bh, Wlz, blz, Wlh, blh, att, uz, cz, uh, ch, probs);
    hipLaunchKernelGGL(partition_kernel, dim3(NBLK2), dim3(256), 0, stream,
                       ei, ew, cur, seg);
    hipLaunchKernelGGL(degdinv_y_kernel, dim3(NB), dim3(256), 0, stream,
                       seg, cur, x, dinv, y);
    hipLaunchKernelGGL(gather_partial_kernel, dim3(NB * SUB), dim3(256), 0, stream,
                       seg, cur, y, part);
    hipLaunchKernelGGL(finalize_kernel, dim3(NB), dim3(256), 0, stream,
                       part, y, dinv, uz, cz, uh, ch, probs, Wout, bout, out);
}

// Round 7
// 156.941 us; speedup vs baseline: 1.4088x; 1.3663x over previous
//
#include <hip/hip_runtime.h>
#include <hip/hip_bf16.h>

// Problem constants (RecurrentGCN / A3TGCN reduction)
constexpr int N_NODES = 20000;
constexpr int P_PER   = 12;
constexpr int N_EDGES = 640000;
constexpr int HID     = 100;

constexpr int BIN_W   = 64;                              // nodes per bin
constexpr int NB      = (N_NODES + BIN_W - 1) / BIN_W;   // 313 bins
constexpr int BCAP    = 2560;                  // per-bin capacity; mean 2048, sigma 45 -> 11 sigma
constexpr int NBLK2   = 320;                   // partition blocks
constexpr int CHUNK   = N_EDGES / NBLK2;       // 2000
constexpr int CUR_STR = 16;                    // cursor padded to one per 64B line
constexpr int Y_STR   = 16;                    // y row stride (floats), 64B-aligned rows

// Workspace layout (4-byte elements)
constexpr size_t OFF_DINV  = 0;                               // N floats
constexpr size_t OFF_UZ    = OFF_DINV + N_NODES;              // 20000
constexpr size_t OFF_CZ    = OFF_UZ + HID;
constexpr size_t OFF_UH    = OFF_CZ + HID;
constexpr size_t OFF_CH    = OFF_UH + HID;
constexpr size_t OFF_PROBS = OFF_CH + HID;                    // 20400..20412
constexpr size_t OFF_CUR   = 20416;                           // NB*CUR_STR ints
constexpr size_t OFF_Y     = OFF_CUR + (size_t)NB * CUR_STR;  // 25424 (16B-aligned), N*Y_STR
constexpr size_t OFF_SEG   = OFF_Y + (size_t)N_NODES * Y_STR; // 345424, NB*BCAP int2
constexpr size_t OFF_SEG2  = OFF_SEG + (size_t)NB * BCAP * 2; // 1947984, NB*BCAP int2 (node-sorted)
constexpr size_t OFF_ROW   = OFF_SEG2 + (size_t)NB * BCAP * 2;// 3550544, N int2 (start,len)
// total ~14.3 MB

// ---------------------------------------------------------------------------
// k1: tiny precompute — rank-1 collapse of (GCN weight @ Wl[:HID]) + softmax(att)
__global__ void precompute_kernel(const float* __restrict__ Wz, const float* __restrict__ bz,
                                  const float* __restrict__ Wh, const float* __restrict__ bh,
                                  const float* __restrict__ Wlz, const float* __restrict__ blz,
                                  const float* __restrict__ Wlh, const float* __restrict__ blh,
                                  const float* __restrict__ att,
                                  float* __restrict__ uz, float* __restrict__ cz,
                                  float* __restrict__ uh, float* __restrict__ ch,
                                  float* __restrict__ probs) {
    int t = threadIdx.x;
    if (t < HID) {
        float suz = 0.f, scz = 0.f, suh = 0.f, sch = 0.f;
        for (int j = 0; j < HID; ++j) {
            float wlz = Wlz[j * HID + t];   // only first HID rows of (2*HID,HID) matter (H0=0)
            float wlh = Wlh[j * HID + t];
            suz += Wz[j] * wlz;
            scz += bz[j] * wlz;
            suh += Wh[j] * wlh;
            sch += bh[j] * wlh;
        }
        uz[t] = suz;
        cz[t] = scz + blz[t];
        uh[t] = suh;
        ch[t] = sch + blh[t];
    }
    if (t == 0) {
        float m = att[0];
        for (int p = 1; p < P_PER; ++p) m = fmaxf(m, att[p]);
        float e[P_PER];
        float s = 0.f;
        for (int p = 0; p < P_PER; ++p) { e[p] = __expf(att[p] - m); s += e[p]; }
        float inv = 1.0f / s;
        for (int p = 0; p < P_PER; ++p) probs[p] = e[p] * inv;
    }
}

// k2: partition edges into NB bins of 64 dst-nodes (coarse counting sort).
// Entry: .x = src | (d_local<<16)  [src < 2^16 since N=20000], .y = weight bits.
__global__ __launch_bounds__(256) void partition_kernel(const int* __restrict__ ei,
                                                        const float* __restrict__ w,
                                                        int* __restrict__ cur,
                                                        int2* __restrict__ seg) {
    __shared__ int hist[NB];
    __shared__ int base[NB];
    __shared__ int run[NB];
    int t = threadIdx.x;
    for (int b = t; b < NB; b += 256) { hist[b] = 0; run[b] = 0; }
    __syncthreads();
    int e0 = blockIdx.x * CHUNK;
    const int* __restrict__ dsts = ei + N_EDGES;
    for (int i = t; i < CHUNK; i += 256) {
        int d = dsts[e0 + i];
        atomicAdd(&hist[d >> 6], 1);
    }
    __syncthreads();
    for (int b = t; b < NB; b += 256) {
        int h = hist[b];
        base[b] = (h > 0) ? atomicAdd(cur + (size_t)b * CUR_STR, h) : 0;
    }
    __syncthreads();
    for (int i = t; i < CHUNK; i += 256) {
        int s = ei[e0 + i];
        int d = dsts[e0 + i];
        float wt = w[e0 + i];
        int b = d >> 6;
        int pos = base[b] + atomicAdd(&run[b], 1);
        if (pos < BCAP)
            seg[(size_t)b * BCAP + pos] = make_int2(s | ((d & 63) << 16), __float_as_int(wt));
    }
}

// k3: per-bin counting sort to node order + wsum/dinv/y, all in LDS.
// LDS atomics: 1 hist + 1 cursor per edge (vs 12 ds_adds in the failed round-6 gather).
__global__ __launch_bounds__(256) void binsort_kernel(const int2* __restrict__ seg,
                                                      const int* __restrict__ cur,
                                                      const float* __restrict__ x,
                                                      float* __restrict__ dinv,
                                                      float* __restrict__ y,
                                                      int2* __restrict__ seg2,
                                                      int2* __restrict__ rowinfo) {
    __shared__ int2 ent[BCAP];       // staged raw entries (20KB)
    __shared__ int2 ent2[BCAP];      // node-sorted entries (20KB)
    __shared__ int  hist[BIN_W];
    __shared__ int  off[BIN_W];
    __shared__ int  excl[BIN_W];
    __shared__ float sdinv[BIN_W];
    int t = threadIdx.x;
    int b = blockIdx.x;
    if (t < BIN_W) hist[t] = 0;
    __syncthreads();
    int c = min(cur[(size_t)b * CUR_STR], BCAP);
    const int2* sg = seg + (size_t)b * BCAP;
    for (int i = t; i < c; i += 256) {
        int2 e = sg[i];
        ent[i] = e;
        atomicAdd(&hist[e.x >> 16], 1);
    }
    __syncthreads();
    // exclusive prefix over 64 counters (wave 0 only, wave64 shuffle scan)
    if (t < 64) {
        int v = hist[t];
        int inc = v;
#pragma unroll
        for (int o = 1; o < 64; o <<= 1) {
            int u = __shfl_up(inc, o, 64);
            if (t >= o) inc += u;
        }
        int ex = inc - v;
        excl[t] = ex;
        off[t]  = ex;
    }
    __syncthreads();
    // scatter into node-sorted order (LDS)
    for (int i = t; i < c; i += 256) {
        int2 e = ent[i];
        int dl = e.x >> 16;
        int p = atomicAdd(&off[dl], 1);
        ent2[p] = make_int2(e.x & 0xFFFF, e.y);
    }
    __syncthreads();
    // wsum per node from sorted runs (no atomics): 4 lanes per node
    {
        int nl = t >> 2, l = t & 3;
        int beg = excl[nl];
        int end = beg + hist[nl];
        float s = 0.f;
        for (int j = beg + l; j < end; j += 4) s += __int_as_float(ent2[j].y);
        s += __shfl_xor(s, 1, 64);
        s += __shfl_xor(s, 2, 64);
        if (l == 0) sdinv[nl] = rsqrtf(1.0f + s);
    }
    __syncthreads();
    int n0 = b * BIN_W;
    // coalesced write of sorted segment
    int2* s2 = seg2 + (size_t)b * BCAP;
    for (int i = t; i < c; i += 256) s2[i] = ent2[i];
    // rowinfo + dinv
    if (t < BIN_W && n0 + t < N_NODES) {
        dinv[n0 + t] = sdinv[t];
        rowinfo[n0 + t] = make_int2(b * BCAP + excl[t], hist[t]);
    }
    // y = dinv * x (padded rows)
    for (int i = t; i < BIN_W * P_PER; i += 256) {
        int nl = i / P_PER, p = i - nl * P_PER;
        int n = n0 + nl;
        if (n < N_NODES) y[(size_t)n * Y_STR + p] = sdinv[nl] * x[(size_t)n * P_PER + p];
    }
}

// k4: gather + fused epilogue. 16 lanes/node, contiguous runs, zero atomics.
//  acc[p] = sum_run w*y[s,p];  a = dinv[n]*(acc + y[n])
//  out[n] = bout + sum_k relu( sum_p probs[p]*sigmoid(-(a*uz+cz))*tanh(a*uh+ch) )*Wout[k]
__global__ __launch_bounds__(256) void gather_finalize_kernel(const int2* __restrict__ seg2,
                                                              const int2* __restrict__ rowinfo,
                                                              const float* __restrict__ y,
                                                              const float* __restrict__ dinv,
                                                              const float* __restrict__ uz,
                                                              const float* __restrict__ cz,
                                                              const float* __restrict__ uh,
                                                              const float* __restrict__ ch,
                                                              const float* __restrict__ probs,
                                                              const float* __restrict__ Wout,
                                                              const float* __restrict__ bout,
                                                              float* __restrict__ out) {
    __shared__ float s_uz[HID], s_cz[HID], s_uh[HID], s_ch[HID], s_wo[HID];
    __shared__ float s_pr[P_PER];
    int t = threadIdx.x;
    if (t < HID) {
        s_uz[t] = uz[t]; s_cz[t] = cz[t];
        s_uh[t] = uh[t]; s_ch[t] = ch[t];
        s_wo[t] = Wout[t];
    }
    if (t < P_PER) s_pr[t] = probs[t];
    __syncthreads();

    int tid = blockIdx.x * blockDim.x + t;
    int n = tid >> 4;
    int l = tid & 15;
    if (n >= N_NODES) return;

    int2 ri = rowinfo[n];              // (start, len)
    float acc[P_PER];
#pragma unroll
    for (int p = 0; p < P_PER; ++p) acc[p] = 0.f;
    int end = ri.x + ri.y;
    for (int j = ri.x + l; j < end; j += 16) {
        int2 e = seg2[j];
        float wt = __int_as_float(e.y);
        const float4* yr = (const float4*)(y + (size_t)e.x * Y_STR);
        float4 y0 = yr[0], y1 = yr[1], y2 = yr[2];
        acc[0]  += wt * y0.x;  acc[1]  += wt * y0.y;
        acc[2]  += wt * y0.z;  acc[3]  += wt * y0.w;
        acc[4]  += wt * y1.x;  acc[5]  += wt * y1.y;
        acc[6]  += wt * y1.z;  acc[7]  += wt * y1.w;
        acc[8]  += wt * y2.x;  acc[9]  += wt * y2.y;
        acc[10] += wt * y2.z;  acc[11] += wt * y2.w;
    }
    // xor-reduce over 16-lane group; all lanes end with full sums
#pragma unroll
    for (int off = 8; off >= 1; off >>= 1) {
#pragma unroll
        for (int p = 0; p < P_PER; ++p) acc[p] += __shfl_xor(acc[p], off, 64);
    }
    {
        float dn = dinv[n];
        const float4* yr = (const float4*)(y + (size_t)n * Y_STR);
        float4 y0 = yr[0], y1 = yr[1], y2 = yr[2];
        acc[0]  = dn * (acc[0]  + y0.x);  acc[1]  = dn * (acc[1]  + y0.y);
        acc[2]  = dn * (acc[2]  + y0.z);  acc[3]  = dn * (acc[3]  + y0.w);
        acc[4]  = dn * (acc[4]  + y1.x);  acc[5]  = dn * (acc[5]  + y1.y);
        acc[6]  = dn * (acc[6]  + y1.z);  acc[7]  = dn * (acc[7]  + y1.w);
        acc[8]  = dn * (acc[8]  + y2.x);  acc[9]  = dn * (acc[9]  + y2.y);
        acc[10] = dn * (acc[10] + y2.z);  acc[11] = dn * (acc[11] + y2.w);
    }
    float rk = 0.f;
    for (int k = l; k < HID; k += 16) {     // 7 or 6 iterations per lane
        float uzk = s_uz[k], czk = s_cz[k], uhk = s_uh[k], chk = s_ch[k];
        float a2 = 0.f;
#pragma unroll
        for (int p = 0; p < P_PER; ++p) {
            float av = acc[p];
            float vz = fminf(fmaxf(av * uzk + czk, -30.f), 30.f);
            float vh = fminf(fmaxf(av * uhk + chk, -15.f), 15.f);
            float ez  = __expf(vz);
            float e2h = __expf(2.0f * vh);
            float term = (e2h - 1.0f) / ((1.0f + ez) * (e2h + 1.0f));  // sigmoid(-vz)*tanh(vh)
            a2 += s_pr[p] * term;
        }
        rk += fmaxf(a2, 0.0f) * s_wo[k];
    }
#pragma unroll
    for (int off = 8; off >= 1; off >>= 1) rk += __shfl_xor(rk, off, 64);
    if (l == 0) out[n] = rk + bout[0];
}

extern "C" void kernel_launch(void* const* d_in, const int* in_sizes, int n_in,
                              void* d_out, int out_size, void* d_ws, size_t ws_size,
                              hipStream_t stream) {
    const float* x   = (const float*)d_in[0];
    const int*   ei  = (const int*)d_in[1];
    const float* ew  = (const float*)d_in[2];
    const float* Wz  = (const float*)d_in[3];
    const float* bz  = (const float*)d_in[4];
    // d_in[5], d_in[6]: W_r, b_r — dead (H0 = 0)
    const float* Wh  = (const float*)d_in[7];
    const float* bh  = (const float*)d_in[8];
    const float* Wlz = (const float*)d_in[9];
    const float* blz = (const float*)d_in[10];
    // d_in[11], d_in[12]: Wl_r, bl_r — dead
    const float* Wlh = (const float*)d_in[13];
    const float* blh = (const float*)d_in[14];
    const float* att = (const float*)d_in[15];
    const float* Wout = (const float*)d_in[16];
    const float* bout = (const float*)d_in[17];
    float* out = (float*)d_out;

    float* ws      = (float*)d_ws;
    float* dinv    = ws + OFF_DINV;
    float* uz      = ws + OFF_UZ;
    float* cz      = ws + OFF_CZ;
    float* uh      = ws + OFF_UH;
    float* ch      = ws + OFF_CH;
    float* probs   = ws + OFF_PROBS;
    int*   cur     = (int*)(ws + OFF_CUR);
    float* y       = ws + OFF_Y;
    int2*  seg     = (int2*)(ws + OFF_SEG);
    int2*  seg2    = (int2*)(ws + OFF_SEG2);
    int2*  rowinfo = (int2*)(ws + OFF_ROW);

    hipMemsetAsync(cur, 0, (size_t)NB * CUR_STR * sizeof(int), stream);
    hipLaunchKernelGGL(precompute_kernel, dim3(1), dim3(128), 0, stream,
                       Wz, bz, Wh, bh, Wlz, blz, Wlh, blh, att, uz, cz, uh, ch, probs);
    hipLaunchKernelGGL(partition_kernel, dim3(NBLK2), dim3(256), 0, stream,
                       ei, ew, cur, seg);
    hipLaunchKernelGGL(binsort_kernel, dim3(NB), dim3(256), 0, stream,
                       seg, cur, x, dinv, y, seg2, rowinfo);
    hipLaunchKernelGGL(gather_finalize_kernel, dim3((N_NODES * 16 + 255) / 256), dim3(256), 0, stream,
                       seg2, rowinfo, y, dinv, uz, cz, uh, ch, probs, Wout, bout, out);
}